// Round 1
// baseline (1482.603 us; speedup 1.0000x reference)
//
#include <hip/hip_runtime.h>
#include <cmath>

#define NB 8
#define NS 2048
#define ND 256
#define NH 8
#define HD 32
#define NM (NB*NS)                  // 16384 rows
#define QK_SCALE 0.17677669529663689f
#define OUT_ATTN ((size_t)NM * ND)  // attn starts after out in d_out

// ---------------------------------------------------------------------------
// Kernel A: QKV projection  x[16384,256] @ w_qkv^T[256,768] + b -> Q,K,V
// head-split layout [B*H, S, HD]; Q prescaled by 1/sqrt(HD).
// ---------------------------------------------------------------------------
__global__ __launch_bounds__(256) void qkv_kernel(
    const float* __restrict__ x, const float* __restrict__ w,
    const float* __restrict__ bias,
    float* __restrict__ Q, float* __restrict__ K, float* __restrict__ V) {
  __shared__ float As[16][68];
  __shared__ float Bs[16][68];
  const int row0 = blockIdx.x * 64;
  const int col0 = blockIdx.y * 64;
  const int tid  = threadIdx.x;
  const int tx = tid & 15, ty = tid >> 4;
  const int lm = tid >> 2, lk = tid & 3;
  float acc[4][4] = {};
  for (int kt = 0; kt < ND; kt += 16) {
    const float4 av = *(const float4*)&x[(size_t)(row0 + lm) * ND + kt + lk * 4];
    const float4 bv = *(const float4*)&w[(size_t)(col0 + lm) * ND + kt + lk * 4];
    __syncthreads();
    As[lk*4+0][lm] = av.x; As[lk*4+1][lm] = av.y; As[lk*4+2][lm] = av.z; As[lk*4+3][lm] = av.w;
    Bs[lk*4+0][lm] = bv.x; Bs[lk*4+1][lm] = bv.y; Bs[lk*4+2][lm] = bv.z; Bs[lk*4+3][lm] = bv.w;
    __syncthreads();
#pragma unroll
    for (int k = 0; k < 16; ++k) {
      const float4 a4 = *(const float4*)&As[k][ty*4];
      const float4 b4 = *(const float4*)&Bs[k][tx*4];
      const float a[4] = {a4.x, a4.y, a4.z, a4.w};
      const float b[4] = {b4.x, b4.y, b4.z, b4.w};
#pragma unroll
      for (int i = 0; i < 4; ++i)
#pragma unroll
        for (int j = 0; j < 4; ++j)
          acc[i][j] = fmaf(a[i], b[j], acc[i][j]);
    }
  }
  const int n0    = col0 + tx * 4;
  const int which = n0 >> 8;          // 0=q 1=k 2=v
  const int dcol  = n0 & 255;
  const int h = dcol >> 5, e0 = dcol & 31;
  float* const dst = (which == 0) ? Q : (which == 1 ? K : V);
  const float scl  = (which == 0) ? QK_SCALE : 1.0f;
  const float bz[4] = {bias[n0], bias[n0+1], bias[n0+2], bias[n0+3]};
#pragma unroll
  for (int i = 0; i < 4; ++i) {
    const int m = row0 + ty * 4 + i;
    const int bb = m >> 11, ss = m & 2047;
    float4 o;
    o.x = (acc[i][0] + bz[0]) * scl;
    o.y = (acc[i][1] + bz[1]) * scl;
    o.z = (acc[i][2] + bz[2]) * scl;
    o.w = (acc[i][3] + bz[3]) * scl;
    *(float4*)&dst[(size_t)((bb * NH + h) * NS + ss) * HD + e0] = o;
  }
}

// ---------------------------------------------------------------------------
// Kernel B: fused causal attention. Block = (q-tile of 64 rows, one b*h).
// Pass1: online max/denom over causal K tiles. Pass2: recompute scores,
// write normalized attn (zeros above diagonal), accumulate PV -> Omid.
// ---------------------------------------------------------------------------
__global__ __launch_bounds__(256) void attn_kernel(
    const float* __restrict__ Q, const float* __restrict__ K,
    const float* __restrict__ V, float* __restrict__ attn,
    float* __restrict__ Omid) {
  __shared__ float QsT[32][68];
  __shared__ float KsT[32][68];
  __shared__ float Vs[64][36];
  __shared__ float Ps[64][65];
  const int qt = blockIdx.x;          // 0..31
  const int bh = blockIdx.y;          // 0..63
  const int q0 = qt * 64;
  const int tid = threadIdx.x;
  const int tx = tid & 15, ty = tid >> 4;
  const int r = tid >> 2, c = tid & 3;
  const float* __restrict__ Qb = Q + (size_t)bh * NS * HD;
  const float* __restrict__ Kb = K + (size_t)bh * NS * HD;
  const float* __restrict__ Vb = V + (size_t)bh * NS * HD;
  {
    const float4 a = *(const float4*)&Qb[(size_t)(q0 + r) * HD + c * 4];
    const float4 b = *(const float4*)&Qb[(size_t)(q0 + r) * HD + 16 + c * 4];
    QsT[c*4+0][r] = a.x; QsT[c*4+1][r] = a.y; QsT[c*4+2][r] = a.z; QsT[c*4+3][r] = a.w;
    QsT[16+c*4+0][r] = b.x; QsT[16+c*4+1][r] = b.y; QsT[16+c*4+2][r] = b.z; QsT[16+c*4+3][r] = b.w;
  }
  float mrow[4] = {-INFINITY, -INFINITY, -INFINITY, -INFINITY};
  float lrow[4] = {0.f, 0.f, 0.f, 0.f};
  __syncthreads();

  // ---------------- pass 1 ----------------
  for (int kt = 0; kt <= qt; ++kt) {
    const int k0 = kt * 64;
    const float4 a = *(const float4*)&Kb[(size_t)(k0 + r) * HD + c * 4];
    const float4 b = *(const float4*)&Kb[(size_t)(k0 + r) * HD + 16 + c * 4];
    __syncthreads();
    KsT[c*4+0][r] = a.x; KsT[c*4+1][r] = a.y; KsT[c*4+2][r] = a.z; KsT[c*4+3][r] = a.w;
    KsT[16+c*4+0][r] = b.x; KsT[16+c*4+1][r] = b.y; KsT[16+c*4+2][r] = b.z; KsT[16+c*4+3][r] = b.w;
    __syncthreads();
    float s[4][4] = {};
#pragma unroll
    for (int kk = 0; kk < 32; ++kk) {
      const float4 a4 = *(const float4*)&QsT[kk][ty*4];
      const float4 b4 = *(const float4*)&KsT[kk][tx*4];
      const float qa[4] = {a4.x, a4.y, a4.z, a4.w};
      const float kb2[4] = {b4.x, b4.y, b4.z, b4.w};
#pragma unroll
      for (int i = 0; i < 4; ++i)
#pragma unroll
        for (int j = 0; j < 4; ++j)
          s[i][j] = fmaf(qa[i], kb2[j], s[i][j]);
    }
    if (kt == qt) {
#pragma unroll
      for (int i = 0; i < 4; ++i)
#pragma unroll
        for (int j = 0; j < 4; ++j)
          if (tx * 4 + j > ty * 4 + i) s[i][j] = -INFINITY;
    }
#pragma unroll
    for (int i = 0; i < 4; ++i) {
      float tm = fmaxf(fmaxf(s[i][0], s[i][1]), fmaxf(s[i][2], s[i][3]));
#pragma unroll
      for (int off = 1; off < 16; off <<= 1) tm = fmaxf(tm, __shfl_xor(tm, off));
      const float mn = fmaxf(mrow[i], tm);
      float ts = __expf(s[i][0]-mn) + __expf(s[i][1]-mn) +
                 __expf(s[i][2]-mn) + __expf(s[i][3]-mn);
#pragma unroll
      for (int off = 1; off < 16; off <<= 1) ts += __shfl_xor(ts, off);
      lrow[i] = lrow[i] * __expf(mrow[i] - mn) + ts;
      mrow[i] = mn;
    }
  }
  float inv_l[4];
#pragma unroll
  for (int i = 0; i < 4; ++i) inv_l[i] = 1.0f / lrow[i];

  // ---------------- pass 2 ----------------
  float o[4][2] = {};
  float* const attnRow = attn + ((size_t)bh * NS + q0) * NS;
  const int d0 = tx * 2;
  for (int kt = 0; kt < NS / 64; ++kt) {
    const int k0 = kt * 64;
    if (kt > qt) {  // fully masked: write zeros (uniform branch per block)
      const float4 z = make_float4(0.f, 0.f, 0.f, 0.f);
#pragma unroll
      for (int i = 0; i < 4; ++i)
        *(float4*)&attnRow[(size_t)(ty*4+i) * NS + k0 + tx*4] = z;
      continue;
    }
    const float4 ka = *(const float4*)&Kb[(size_t)(k0 + r) * HD + c * 4];
    const float4 kb = *(const float4*)&Kb[(size_t)(k0 + r) * HD + 16 + c * 4];
    const float4 va = *(const float4*)&Vb[(size_t)(k0 + r) * HD + c * 4];
    const float4 vb = *(const float4*)&Vb[(size_t)(k0 + r) * HD + 16 + c * 4];
    __syncthreads();   // previous PV reads done
    KsT[c*4+0][r] = ka.x; KsT[c*4+1][r] = ka.y; KsT[c*4+2][r] = ka.z; KsT[c*4+3][r] = ka.w;
    KsT[16+c*4+0][r] = kb.x; KsT[16+c*4+1][r] = kb.y; KsT[16+c*4+2][r] = kb.z; KsT[16+c*4+3][r] = kb.w;
    *(float4*)&Vs[r][c*4]      = va;
    *(float4*)&Vs[r][16 + c*4] = vb;
    __syncthreads();
    float s[4][4] = {};
#pragma unroll
    for (int kk = 0; kk < 32; ++kk) {
      const float4 a4 = *(const float4*)&QsT[kk][ty*4];
      const float4 b4 = *(const float4*)&KsT[kk][tx*4];
      const float qa[4] = {a4.x, a4.y, a4.z, a4.w};
      const float kb2[4] = {b4.x, b4.y, b4.z, b4.w};
#pragma unroll
      for (int i = 0; i < 4; ++i)
#pragma unroll
        for (int j = 0; j < 4; ++j)
          s[i][j] = fmaf(qa[i], kb2[j], s[i][j]);
    }
    if (kt == qt) {
#pragma unroll
      for (int i = 0; i < 4; ++i)
#pragma unroll
        for (int j = 0; j < 4; ++j)
          if (tx * 4 + j > ty * 4 + i) s[i][j] = -INFINITY;
    }
#pragma unroll
    for (int i = 0; i < 4; ++i) {
      float4 p4;
      p4.x = __expf(s[i][0] - mrow[i]) * inv_l[i];
      p4.y = __expf(s[i][1] - mrow[i]) * inv_l[i];
      p4.z = __expf(s[i][2] - mrow[i]) * inv_l[i];
      p4.w = __expf(s[i][3] - mrow[i]) * inv_l[i];
      *(float4*)&attnRow[(size_t)(ty*4+i) * NS + k0 + tx*4] = p4;
      Ps[ty*4+i][tx*4+0] = p4.x; Ps[ty*4+i][tx*4+1] = p4.y;
      Ps[ty*4+i][tx*4+2] = p4.z; Ps[ty*4+i][tx*4+3] = p4.w;
    }
    __syncthreads();
#pragma unroll 8
    for (int k = 0; k < 64; ++k) {
      const float2 vv = *(const float2*)&Vs[k][d0];
#pragma unroll
      for (int i = 0; i < 4; ++i) {
        const float p = Ps[ty*4+i][k];
        o[i][0] = fmaf(p, vv.x, o[i][0]);
        o[i][1] = fmaf(p, vv.y, o[i][1]);
      }
    }
  }
  const int bb = bh >> 3, hh = bh & 7;
#pragma unroll
  for (int i = 0; i < 4; ++i) {
    float2 ov; ov.x = o[i][0]; ov.y = o[i][1];
    *(float2*)&Omid[(size_t)(bb * NS + q0 + ty*4 + i) * ND + hh * HD + d0] = ov;
  }
}

// ---------------------------------------------------------------------------
// Kernel C: output projection  Omid[16384,256] @ w_out^T + b_out -> out
// ---------------------------------------------------------------------------
__global__ __launch_bounds__(256) void proj_kernel(
    const float* __restrict__ a_in, const float* __restrict__ w,
    const float* __restrict__ bias, float* __restrict__ out) {
  __shared__ float As[16][68];
  __shared__ float Bs[16][68];
  const int row0 = blockIdx.x * 64;
  const int col0 = blockIdx.y * 64;
  const int tid  = threadIdx.x;
  const int tx = tid & 15, ty = tid >> 4;
  const int lm = tid >> 2, lk = tid & 3;
  float acc[4][4] = {};
  for (int kt = 0; kt < ND; kt += 16) {
    const float4 av = *(const float4*)&a_in[(size_t)(row0 + lm) * ND + kt + lk * 4];
    const float4 bv = *(const float4*)&w[(size_t)(col0 + lm) * ND + kt + lk * 4];
    __syncthreads();
    As[lk*4+0][lm] = av.x; As[lk*4+1][lm] = av.y; As[lk*4+2][lm] = av.z; As[lk*4+3][lm] = av.w;
    Bs[lk*4+0][lm] = bv.x; Bs[lk*4+1][lm] = bv.y; Bs[lk*4+2][lm] = bv.z; Bs[lk*4+3][lm] = bv.w;
    __syncthreads();
#pragma unroll
    for (int k = 0; k < 16; ++k) {
      const float4 a4 = *(const float4*)&As[k][ty*4];
      const float4 b4 = *(const float4*)&Bs[k][tx*4];
      const float a[4] = {a4.x, a4.y, a4.z, a4.w};
      const float b[4] = {b4.x, b4.y, b4.z, b4.w};
#pragma unroll
      for (int i = 0; i < 4; ++i)
#pragma unroll
        for (int j = 0; j < 4; ++j)
          acc[i][j] = fmaf(a[i], b[j], acc[i][j]);
    }
  }
  const int n0 = col0 + tx * 4;
  const float bz[4] = {bias[n0], bias[n0+1], bias[n0+2], bias[n0+3]};
#pragma unroll
  for (int i = 0; i < 4; ++i) {
    float4 o;
    o.x = acc[i][0] + bz[0];
    o.y = acc[i][1] + bz[1];
    o.z = acc[i][2] + bz[2];
    o.w = acc[i][3] + bz[3];
    *(float4*)&out[(size_t)(row0 + ty*4 + i) * ND + n0] = o;
  }
}

// ---------------------------------------------------------------------------
extern "C" void kernel_launch(void* const* d_in, const int* in_sizes, int n_in,
                              void* d_out, int out_size, void* d_ws, size_t ws_size,
                              hipStream_t stream) {
  const float* x     = (const float*)d_in[0];
  const float* w_qkv = (const float*)d_in[1];
  const float* b_qkv = (const float*)d_in[2];
  const float* w_out = (const float*)d_in[3];
  const float* b_out = (const float*)d_in[4];
  float* out  = (float*)d_out;
  float* attn = out + OUT_ATTN;

  float* ws   = (float*)d_ws;
  const size_t SZ = (size_t)NB * NH * NS * HD;  // 4,194,304 floats per tensor
  float* Qbuf = ws;
  float* Kbuf = ws + SZ;
  float* Vbuf = ws + 2 * SZ;
  float* Omid = ws + 3 * SZ;

  qkv_kernel<<<dim3(NM / 64, 768 / 64), 256, 0, stream>>>(x, w_qkv, b_qkv, Qbuf, Kbuf, Vbuf);
  attn_kernel<<<dim3(NS / 64, NB * NH), 256, 0, stream>>>(Qbuf, Kbuf, Vbuf, attn, Omid);
  proj_kernel<<<dim3(NM / 64, ND / 64), 256, 0, stream>>>(Omid, w_out, b_out, out);
}

// Round 2
// 656.269 us; speedup vs baseline: 2.2591x; 2.2591x over previous
//
#include <hip/hip_runtime.h>
#include <cmath>

#define NB 8
#define NS 2048
#define ND 256
#define NH 8
#define HD 32
#define NM (NB*NS)                  // 16384 rows
#define QK_SCALE 0.17677669529663689f
#define OUT_ATTN ((size_t)NM * ND)  // attn starts after out in d_out

// ---------------------------------------------------------------------------
// Kernel A: QKV projection  x[16384,256] @ w_qkv^T[256,768] + b -> Q,K,V
// head-split layout [B*H, S, HD]; Q prescaled by 1/sqrt(HD).
// ---------------------------------------------------------------------------
__global__ __launch_bounds__(256) void qkv_kernel(
    const float* __restrict__ x, const float* __restrict__ w,
    const float* __restrict__ bias,
    float* __restrict__ Q, float* __restrict__ K, float* __restrict__ V) {
  __shared__ float As[16][68];
  __shared__ float Bs[16][68];
  const int row0 = blockIdx.x * 64;
  const int col0 = blockIdx.y * 64;
  const int tid  = threadIdx.x;
  const int tx = tid & 15, ty = tid >> 4;
  const int lm = tid >> 2, lk = tid & 3;
  float acc[4][4] = {};
  for (int kt = 0; kt < ND; kt += 16) {
    const float4 av = *(const float4*)&x[(size_t)(row0 + lm) * ND + kt + lk * 4];
    const float4 bv = *(const float4*)&w[(size_t)(col0 + lm) * ND + kt + lk * 4];
    __syncthreads();
    As[lk*4+0][lm] = av.x; As[lk*4+1][lm] = av.y; As[lk*4+2][lm] = av.z; As[lk*4+3][lm] = av.w;
    Bs[lk*4+0][lm] = bv.x; Bs[lk*4+1][lm] = bv.y; Bs[lk*4+2][lm] = bv.z; Bs[lk*4+3][lm] = bv.w;
    __syncthreads();
#pragma unroll
    for (int k = 0; k < 16; ++k) {
      const float4 a4 = *(const float4*)&As[k][ty*4];
      const float4 b4 = *(const float4*)&Bs[k][tx*4];
      const float a[4] = {a4.x, a4.y, a4.z, a4.w};
      const float b[4] = {b4.x, b4.y, b4.z, b4.w};
#pragma unroll
      for (int i = 0; i < 4; ++i)
#pragma unroll
        for (int j = 0; j < 4; ++j)
          acc[i][j] = fmaf(a[i], b[j], acc[i][j]);
    }
  }
  const int n0    = col0 + tx * 4;
  const int which = n0 >> 8;          // 0=q 1=k 2=v
  const int dcol  = n0 & 255;
  const int h = dcol >> 5, e0 = dcol & 31;
  float* const dst = (which == 0) ? Q : (which == 1 ? K : V);
  const float scl  = (which == 0) ? QK_SCALE : 1.0f;
  const float bz[4] = {bias[n0], bias[n0+1], bias[n0+2], bias[n0+3]};
#pragma unroll
  for (int i = 0; i < 4; ++i) {
    const int m = row0 + ty * 4 + i;
    const int bb = m >> 11, ss = m & 2047;
    float4 o;
    o.x = (acc[i][0] + bz[0]) * scl;
    o.y = (acc[i][1] + bz[1]) * scl;
    o.z = (acc[i][2] + bz[2]) * scl;
    o.w = (acc[i][3] + bz[3]) * scl;
    *(float4*)&dst[(size_t)((bb * NH + h) * NS + ss) * HD + e0] = o;
  }
}

// ---------------------------------------------------------------------------
// Kernel B: fused causal attention. Block = (one b*h, q-tile of 64 rows).
// qt remapped heavy-first; bh fastest-varying => same-bh blocks share an XCD.
// Pass1: online max + per-lane partial denom over causal K tiles (prefetched).
// Pass2: recompute scores, write normalized attn, accumulate PV.
// ---------------------------------------------------------------------------
__global__ __launch_bounds__(256) void attn_kernel(
    const float* __restrict__ Q, const float* __restrict__ K,
    const float* __restrict__ V, float* __restrict__ attn,
    float* __restrict__ Omid) {
  __shared__ float QsT[32][68];   // 8.7 KB  (transposed: [d][row])
  __shared__ float KsT[32][68];   // 8.7 KB  (transposed: [d][k])
  __shared__ float Vs[64][36];    // 9.2 KB  ([k][d])
  __shared__ float Ps[64][68];    // 17.4 KB ([row][k], 16B-aligned rows)
  const int bh = blockIdx.x;                 // 0..63  (fast-varying -> XCD)
  const int qt = (NS / 64 - 1) - blockIdx.y; // heavy tiles dispatched first
  const int q0 = qt * 64;
  const int tid = threadIdx.x;
  const int tx = tid & 15, ty = tid >> 4;
  const int r = tid >> 2, c = tid & 3;
  const float* __restrict__ Qb = Q + (size_t)bh * NS * HD;
  const float* __restrict__ Kb = K + (size_t)bh * NS * HD;
  const float* __restrict__ Vb = V + (size_t)bh * NS * HD;

  // Q tile -> LDS (transposed)
  {
    const float4 a = *(const float4*)&Qb[(size_t)(q0 + r) * HD + c * 4];
    const float4 b = *(const float4*)&Qb[(size_t)(q0 + r) * HD + 16 + c * 4];
    QsT[c*4+0][r] = a.x; QsT[c*4+1][r] = a.y; QsT[c*4+2][r] = a.z; QsT[c*4+3][r] = a.w;
    QsT[16+c*4+0][r] = b.x; QsT[16+c*4+1][r] = b.y; QsT[16+c*4+2][r] = b.z; QsT[16+c*4+3][r] = b.w;
  }

  float mrow[4] = {-INFINITY, -INFINITY, -INFINITY, -INFINITY};
  float lpar[4] = {0.f, 0.f, 0.f, 0.f};   // per-lane partial denominators

  float4 ka, kb, va, vb;
  // prefetch K tile 0 (pass 1)
  ka = *(const float4*)&Kb[(size_t)(r) * HD + c * 4];
  kb = *(const float4*)&Kb[(size_t)(r) * HD + 16 + c * 4];

  // ---------------- pass 1: row max + denom ----------------
  for (int kt = 0; kt <= qt; ++kt) {
    __syncthreads();                       // prev QK reads done (also covers QsT)
    KsT[c*4+0][r] = ka.x; KsT[c*4+1][r] = ka.y; KsT[c*4+2][r] = ka.z; KsT[c*4+3][r] = ka.w;
    KsT[16+c*4+0][r] = kb.x; KsT[16+c*4+1][r] = kb.y; KsT[16+c*4+2][r] = kb.z; KsT[16+c*4+3][r] = kb.w;
    __syncthreads();
    if (kt < qt) {                         // prefetch next tile: latency hides under QK
      const int k0n = (kt + 1) * 64;
      ka = *(const float4*)&Kb[(size_t)(k0n + r) * HD + c * 4];
      kb = *(const float4*)&Kb[(size_t)(k0n + r) * HD + 16 + c * 4];
    }
    float s[4][4] = {};
#pragma unroll
    for (int kk = 0; kk < 32; ++kk) {
      const float4 a4 = *(const float4*)&QsT[kk][ty*4];
      const float4 b4 = *(const float4*)&KsT[kk][tx*4];
      const float qa[4] = {a4.x, a4.y, a4.z, a4.w};
      const float kb2[4] = {b4.x, b4.y, b4.z, b4.w};
#pragma unroll
      for (int i = 0; i < 4; ++i)
#pragma unroll
        for (int j = 0; j < 4; ++j)
          s[i][j] = fmaf(qa[i], kb2[j], s[i][j]);
    }
    if (kt == qt) {
#pragma unroll
      for (int i = 0; i < 4; ++i)
#pragma unroll
        for (int j = 0; j < 4; ++j)
          if (tx * 4 + j > ty * 4 + i) s[i][j] = -INFINITY;
    }
#pragma unroll
    for (int i = 0; i < 4; ++i) {
      float tm = fmaxf(fmaxf(s[i][0], s[i][1]), fmaxf(s[i][2], s[i][3]));
#pragma unroll
      for (int off = 1; off < 16; off <<= 1) tm = fmaxf(tm, __shfl_xor(tm, off));
      const float mn = fmaxf(mrow[i], tm);
      // per-lane partial sum; reduced across the 16-lane row group once at end
      lpar[i] = lpar[i] * __expf(mrow[i] - mn) +
                __expf(s[i][0]-mn) + __expf(s[i][1]-mn) +
                __expf(s[i][2]-mn) + __expf(s[i][3]-mn);
      mrow[i] = mn;
    }
  }
  float inv_l[4];
#pragma unroll
  for (int i = 0; i < 4; ++i) {
    float ls = lpar[i];
#pragma unroll
    for (int off = 1; off < 16; off <<= 1) ls += __shfl_xor(ls, off);
    inv_l[i] = 1.0f / ls;
  }

  // ---------------- pass 2: write normalized attn + PV ----------------
  float o[4][2] = {};
  float* const attnRow = attn + ((size_t)bh * NS + q0) * NS;
  const int d0 = tx * 2;
  // prefetch K,V tile 0
  ka = *(const float4*)&Kb[(size_t)(r) * HD + c * 4];
  kb = *(const float4*)&Kb[(size_t)(r) * HD + 16 + c * 4];
  va = *(const float4*)&Vb[(size_t)(r) * HD + c * 4];
  vb = *(const float4*)&Vb[(size_t)(r) * HD + 16 + c * 4];

  for (int kt = 0; kt < NS / 64; ++kt) {
    const int k0 = kt * 64;
    if (kt > qt) {  // fully masked: write zeros (block-uniform branch, no barriers)
      const float4 z = make_float4(0.f, 0.f, 0.f, 0.f);
#pragma unroll
      for (int i = 0; i < 4; ++i)
        *(float4*)&attnRow[(size_t)(ty*4+i) * NS + k0 + tx*4] = z;
      continue;
    }
    __syncthreads();   // previous tile's PV/QK LDS reads done
    KsT[c*4+0][r] = ka.x; KsT[c*4+1][r] = ka.y; KsT[c*4+2][r] = ka.z; KsT[c*4+3][r] = ka.w;
    KsT[16+c*4+0][r] = kb.x; KsT[16+c*4+1][r] = kb.y; KsT[16+c*4+2][r] = kb.z; KsT[16+c*4+3][r] = kb.w;
    *(float4*)&Vs[r][c*4]      = va;
    *(float4*)&Vs[r][16 + c*4] = vb;
    __syncthreads();
    if (kt < qt) {     // prefetch next tile under this tile's compute
      const int k0n = k0 + 64;
      ka = *(const float4*)&Kb[(size_t)(k0n + r) * HD + c * 4];
      kb = *(const float4*)&Kb[(size_t)(k0n + r) * HD + 16 + c * 4];
      va = *(const float4*)&Vb[(size_t)(k0n + r) * HD + c * 4];
      vb = *(const float4*)&Vb[(size_t)(k0n + r) * HD + 16 + c * 4];
    }
    float s[4][4] = {};
#pragma unroll
    for (int kk = 0; kk < 32; ++kk) {
      const float4 a4 = *(const float4*)&QsT[kk][ty*4];
      const float4 b4 = *(const float4*)&KsT[kk][tx*4];
      const float qa[4] = {a4.x, a4.y, a4.z, a4.w};
      const float kb2[4] = {b4.x, b4.y, b4.z, b4.w};
#pragma unroll
      for (int i = 0; i < 4; ++i)
#pragma unroll
        for (int j = 0; j < 4; ++j)
          s[i][j] = fmaf(qa[i], kb2[j], s[i][j]);
    }
    if (kt == qt) {
#pragma unroll
      for (int i = 0; i < 4; ++i)
#pragma unroll
        for (int j = 0; j < 4; ++j)
          if (tx * 4 + j > ty * 4 + i) s[i][j] = -INFINITY;
    }
#pragma unroll
    for (int i = 0; i < 4; ++i) {
      float4 p4;
      p4.x = __expf(s[i][0] - mrow[i]) * inv_l[i];
      p4.y = __expf(s[i][1] - mrow[i]) * inv_l[i];
      p4.z = __expf(s[i][2] - mrow[i]) * inv_l[i];
      p4.w = __expf(s[i][3] - mrow[i]) * inv_l[i];
      *(float4*)&attnRow[(size_t)(ty*4+i) * NS + k0 + tx*4] = p4;
      *(float4*)&Ps[ty*4+i][tx*4] = p4;   // wave-local produce/consume: no barrier
    }
    // PV: float4 P reads (broadcast) + shared V reads
#pragma unroll
    for (int k4 = 0; k4 < 16; ++k4) {
      float pk[4][4];
#pragma unroll
      for (int i = 0; i < 4; ++i) {
        const float4 pv4 = *(const float4*)&Ps[ty*4+i][k4*4];
        pk[i][0] = pv4.x; pk[i][1] = pv4.y; pk[i][2] = pv4.z; pk[i][3] = pv4.w;
      }
#pragma unroll
      for (int kk = 0; kk < 4; ++kk) {
        const float2 vv = *(const float2*)&Vs[k4*4+kk][d0];
#pragma unroll
        for (int i = 0; i < 4; ++i) {
          o[i][0] = fmaf(pk[i][kk], vv.x, o[i][0]);
          o[i][1] = fmaf(pk[i][kk], vv.y, o[i][1]);
        }
      }
    }
  }
  const int bb = bh >> 3, hh = bh & 7;
#pragma unroll
  for (int i = 0; i < 4; ++i) {
    float2 ov; ov.x = o[i][0]; ov.y = o[i][1];
    *(float2*)&Omid[(size_t)(bb * NS + q0 + ty*4 + i) * ND + hh * HD + d0] = ov;
  }
}

// ---------------------------------------------------------------------------
// Kernel C: output projection  Omid[16384,256] @ w_out^T + b_out -> out
// ---------------------------------------------------------------------------
__global__ __launch_bounds__(256) void proj_kernel(
    const float* __restrict__ a_in, const float* __restrict__ w,
    const float* __restrict__ bias, float* __restrict__ out) {
  __shared__ float As[16][68];
  __shared__ float Bs[16][68];
  const int row0 = blockIdx.x * 64;
  const int col0 = blockIdx.y * 64;
  const int tid  = threadIdx.x;
  const int tx = tid & 15, ty = tid >> 4;
  const int lm = tid >> 2, lk = tid & 3;
  float acc[4][4] = {};
  for (int kt = 0; kt < ND; kt += 16) {
    const float4 av = *(const float4*)&a_in[(size_t)(row0 + lm) * ND + kt + lk * 4];
    const float4 bv = *(const float4*)&w[(size_t)(col0 + lm) * ND + kt + lk * 4];
    __syncthreads();
    As[lk*4+0][lm] = av.x; As[lk*4+1][lm] = av.y; As[lk*4+2][lm] = av.z; As[lk*4+3][lm] = av.w;
    Bs[lk*4+0][lm] = bv.x; Bs[lk*4+1][lm] = bv.y; Bs[lk*4+2][lm] = bv.z; Bs[lk*4+3][lm] = bv.w;
    __syncthreads();
#pragma unroll
    for (int k = 0; k < 16; ++k) {
      const float4 a4 = *(const float4*)&As[k][ty*4];
      const float4 b4 = *(const float4*)&Bs[k][tx*4];
      const float a[4] = {a4.x, a4.y, a4.z, a4.w};
      const float b[4] = {b4.x, b4.y, b4.z, b4.w};
#pragma unroll
      for (int i = 0; i < 4; ++i)
#pragma unroll
        for (int j = 0; j < 4; ++j)
          acc[i][j] = fmaf(a[i], b[j], acc[i][j]);
    }
  }
  const int n0 = col0 + tx * 4;
  const float bz[4] = {bias[n0], bias[n0+1], bias[n0+2], bias[n0+3]};
#pragma unroll
  for (int i = 0; i < 4; ++i) {
    float4 o;
    o.x = acc[i][0] + bz[0];
    o.y = acc[i][1] + bz[1];
    o.z = acc[i][2] + bz[2];
    o.w = acc[i][3] + bz[3];
    *(float4*)&out[(size_t)(row0 + ty*4 + i) * ND + n0] = o;
  }
}

// ---------------------------------------------------------------------------
extern "C" void kernel_launch(void* const* d_in, const int* in_sizes, int n_in,
                              void* d_out, int out_size, void* d_ws, size_t ws_size,
                              hipStream_t stream) {
  const float* x     = (const float*)d_in[0];
  const float* w_qkv = (const float*)d_in[1];
  const float* b_qkv = (const float*)d_in[2];
  const float* w_out = (const float*)d_in[3];
  const float* b_out = (const float*)d_in[4];
  float* out  = (float*)d_out;
  float* attn = out + OUT_ATTN;

  float* ws   = (float*)d_ws;
  const size_t SZ = (size_t)NB * NH * NS * HD;  // 4,194,304 floats per tensor
  float* Qbuf = ws;
  float* Kbuf = ws + SZ;
  float* Vbuf = ws + 2 * SZ;
  float* Omid = ws + 3 * SZ;

  qkv_kernel<<<dim3(NM / 64, 768 / 64), 256, 0, stream>>>(x, w_qkv, b_qkv, Qbuf, Kbuf, Vbuf);
  attn_kernel<<<dim3(NB * NH, NS / 64), 256, 0, stream>>>(Qbuf, Kbuf, Vbuf, attn, Omid);
  proj_kernel<<<dim3(NM / 64, ND / 64), 256, 0, stream>>>(Omid, w_out, b_out, out);
}

// Round 3
// 470.294 us; speedup vs baseline: 3.1525x; 1.3954x over previous
//
#include <hip/hip_runtime.h>
#include <cmath>

#define NB 8
#define NS 2048
#define ND 256
#define NH 8
#define HD 32
#define NM (NB*NS)                  // 16384 rows
#define QK_SCALE 0.17677669529663689f
#define OUT_ATTN ((size_t)NM * ND)  // attn starts after out in d_out

typedef __attribute__((ext_vector_type(8))) short bf16x8;
typedef __attribute__((ext_vector_type(4))) float f32x4;

__device__ __forceinline__ ushort f2b(float f) {
  union { float f; uint32_t u; } v; v.f = f;
  const uint32_t r = (v.u + 0x7FFFu + ((v.u >> 16) & 1u)) >> 16;  // RNE
  return (ushort)r;
}

// ---------------------------------------------------------------------------
// Kernel A: QKV projection  x[16384,256] @ w_qkv^T + b.
// Emits bf16: Q [bh][s][32] (prescaled by 1/sqrt(HD)), K [bh][s][32],
// V TRANSPOSED [bh][d=32][s=2048]  (so attn reads V as MFMA B-frags directly).
// ---------------------------------------------------------------------------
__global__ __launch_bounds__(256) void qkv_kernel(
    const float* __restrict__ x, const float* __restrict__ w,
    const float* __restrict__ bias,
    ushort* __restrict__ Qb, ushort* __restrict__ Kb, ushort* __restrict__ Vt) {
  __shared__ float As[16][68];
  __shared__ float Bs[16][68];
  const int row0 = blockIdx.x * 64;
  const int col0 = blockIdx.y * 64;
  const int tid  = threadIdx.x;
  const int tx = tid & 15, ty = tid >> 4;
  const int lm = tid >> 2, lk = tid & 3;
  float acc[4][4] = {};
  for (int kt = 0; kt < ND; kt += 16) {
    const float4 av = *(const float4*)&x[(size_t)(row0 + lm) * ND + kt + lk * 4];
    const float4 bv = *(const float4*)&w[(size_t)(col0 + lm) * ND + kt + lk * 4];
    __syncthreads();
    As[lk*4+0][lm] = av.x; As[lk*4+1][lm] = av.y; As[lk*4+2][lm] = av.z; As[lk*4+3][lm] = av.w;
    Bs[lk*4+0][lm] = bv.x; Bs[lk*4+1][lm] = bv.y; Bs[lk*4+2][lm] = bv.z; Bs[lk*4+3][lm] = bv.w;
    __syncthreads();
#pragma unroll
    for (int k = 0; k < 16; ++k) {
      const float4 a4 = *(const float4*)&As[k][ty*4];
      const float4 b4 = *(const float4*)&Bs[k][tx*4];
      const float a[4] = {a4.x, a4.y, a4.z, a4.w};
      const float b[4] = {b4.x, b4.y, b4.z, b4.w};
#pragma unroll
      for (int i = 0; i < 4; ++i)
#pragma unroll
        for (int j = 0; j < 4; ++j)
          acc[i][j] = fmaf(a[i], b[j], acc[i][j]);
    }
  }
  const int n0    = col0 + tx * 4;
  const int which = n0 >> 8;          // 0=q 1=k 2=v
  const int dcol  = n0 & 255;
  const int h = dcol >> 5, e0 = dcol & 31;
  const float scl = (which == 0) ? QK_SCALE : 1.0f;
  const float bz[4] = {bias[n0], bias[n0+1], bias[n0+2], bias[n0+3]};
  if (which < 2) {
    ushort* const dst = (which == 0) ? Qb : Kb;
#pragma unroll
    for (int i = 0; i < 4; ++i) {
      const int m = row0 + ty * 4 + i;
      const int bb = m >> 11, ss = m & 2047;
      ushort4 o;
      o.x = f2b((acc[i][0] + bz[0]) * scl);
      o.y = f2b((acc[i][1] + bz[1]) * scl);
      o.z = f2b((acc[i][2] + bz[2]) * scl);
      o.w = f2b((acc[i][3] + bz[3]) * scl);
      *(ushort4*)&dst[(size_t)((bb * NH + h) * NS + ss) * HD + e0] = o;
    }
  } else {
    const int m0 = row0 + ty * 4;            // 4 consecutive s values
    const int bb = m0 >> 11, ss0 = m0 & 2047;
#pragma unroll
    for (int j = 0; j < 4; ++j) {
      ushort4 o;
      o.x = f2b(acc[0][j] + bz[j]);
      o.y = f2b(acc[1][j] + bz[j]);
      o.z = f2b(acc[2][j] + bz[j]);
      o.w = f2b(acc[3][j] + bz[j]);
      *(ushort4*)&Vt[(size_t)((bb * NH + h) * HD + e0 + j) * NS + ss0] = o;
    }
  }
}

// ---------------------------------------------------------------------------
// Kernel B: MFMA causal attention. Block = 4 independent waves; wave w owns
// q rows [q0+w*16, q0+w*16+16). No barriers. Q/K/V fragments loaded straight
// from global (L2-hot bf16). Two passes: (1) row max+denoms, (2) recompute,
// write normalized attn (fp32) + PV via MFMA.
// Fragment maps (16x16x32): A row = lane%16, B col = lane%16, k = 8*(l>>4)+i;
// D: col = lane&15, row = (lane>>4)*4 + r   [m89-verified].
// ---------------------------------------------------------------------------
__global__ __launch_bounds__(256) void attn_kernel(
    const ushort* __restrict__ Qb, const ushort* __restrict__ Kb,
    const ushort* __restrict__ Vt, float* __restrict__ attn,
    float* __restrict__ Omid) {
  __shared__ float Ps[64][68];   // pad 68: all patterns at bank floor
  const int bh = blockIdx.x;                 // fast-varying -> XCD spread, K/V L2-resident
  const int qt = (NS / 64 - 1) - blockIdx.y; // heavy tiles first
  const int q0 = qt * 64;
  const int lane = threadIdx.x & 63;
  const int w    = threadIdx.x >> 6;   // wave 0..3
  const int a    = lane & 15;
  const int qd   = lane >> 4;
  const ushort* __restrict__ Qh = Qb + (size_t)bh * NS * HD;
  const ushort* __restrict__ Kh = Kb + (size_t)bh * NS * HD;
  const ushort* __restrict__ Vh = Vt + (size_t)bh * HD * NS;

  const f32x4 zero4 = {0.f, 0.f, 0.f, 0.f};
  // Q fragment: row = w*16+a, k = qd*8..qd*8+7 (16B global load, once)
  const bf16x8 qf = *(const bf16x8*)&Qh[(size_t)(q0 + w*16 + a) * HD + qd*8];

  float mrow[4] = {-INFINITY, -INFINITY, -INFINITY, -INFINITY};
  float lpar[4] = {0.f, 0.f, 0.f, 0.f};

  // ---------------- pass 1: row max + denom ----------------
  for (int kt = 0; kt <= qt; ++kt) {
    const int k0 = kt * 64;
    const bool diag = (kt == qt);
    f32x4 s[4];
#pragma unroll
    for (int jt = 0; jt < 4; ++jt) {
      if (!diag || jt <= w) {
        const bf16x8 kf = *(const bf16x8*)&Kh[(size_t)(k0 + jt*16 + a) * HD + qd*8];
        s[jt] = __builtin_amdgcn_mfma_f32_16x16x32_bf16(qf, kf, zero4, 0, 0, 0);
        if (diag && jt == w) {
#pragma unroll
          for (int r = 0; r < 4; ++r)
            if (a > qd*4 + r) s[jt][r] = -INFINITY;   // key > query
        }
      } else {
        s[jt] = (f32x4){-INFINITY, -INFINITY, -INFINITY, -INFINITY};
      }
    }
#pragma unroll
    for (int r = 0; r < 4; ++r) {
      float tm = fmaxf(fmaxf(s[0][r], s[1][r]), fmaxf(s[2][r], s[3][r]));
#pragma unroll
      for (int off = 1; off < 16; off <<= 1) tm = fmaxf(tm, __shfl_xor(tm, off));
      const float mn = fmaxf(mrow[r], tm);
      lpar[r] = lpar[r] * __expf(mrow[r] - mn) +
                __expf(s[0][r] - mn) + __expf(s[1][r] - mn) +
                __expf(s[2][r] - mn) + __expf(s[3][r] - mn);
      mrow[r] = mn;
    }
  }
  float inv_l[4];
#pragma unroll
  for (int r = 0; r < 4; ++r) {
    float ls = lpar[r];
#pragma unroll
    for (int off = 1; off < 16; off <<= 1) ls += __shfl_xor(ls, off);
    inv_l[r] = 1.0f / ls;
  }

  // ---------------- pass 2: normalized attn write + PV ----------------
  f32x4 oc0 = zero4, oc1 = zero4;
  float* const attnRow = attn + ((size_t)bh * NS + q0) * NS;

  for (int kt = 0; kt < NS / 64; ++kt) {
    const int k0 = kt * 64;
    if (kt > qt) {   // fully masked: stream zeros (no LDS, no MFMA)
      const float4 z = make_float4(0.f, 0.f, 0.f, 0.f);
#pragma unroll
      for (int i = 0; i < 4; ++i)
        *(float4*)&attnRow[(size_t)(w*16 + i*4 + qd) * NS + k0 + a*4] = z;
      continue;
    }
    const bool diag = (kt == qt);
    f32x4 s[4];
#pragma unroll
    for (int jt = 0; jt < 4; ++jt) {
      if (!diag || jt <= w) {
        const bf16x8 kf = *(const bf16x8*)&Kh[(size_t)(k0 + jt*16 + a) * HD + qd*8];
        s[jt] = __builtin_amdgcn_mfma_f32_16x16x32_bf16(qf, kf, zero4, 0, 0, 0);
        if (diag && jt == w) {
#pragma unroll
          for (int r = 0; r < 4; ++r)
            if (a > qd*4 + r) s[jt][r] = -INFINITY;
        }
      } else {
        s[jt] = (f32x4){-INFINITY, -INFINITY, -INFINITY, -INFINITY};
      }
    }
    // P -> LDS (wave-own 16-row slab; masked entries become exact 0)
#pragma unroll
    for (int jt = 0; jt < 4; ++jt)
#pragma unroll
      for (int r = 0; r < 4; ++r)
        Ps[w*16 + qd*4 + r][jt*16 + a] = __expf(s[jt][r] - mrow[r]) * inv_l[r];

    // coalesced fp32 attn write from LDS (wave-local, in-order LDS per wave)
#pragma unroll
    for (int i = 0; i < 4; ++i) {
      const int row16 = i*4 + qd;
      *(float4*)&attnRow[(size_t)(w*16 + row16) * NS + k0 + a*4] =
          *(const float4*)&Ps[w*16 + row16][a*4];
    }

    // PV: A = P (rows w*16+a, k=8*qd+i per 32-half), B = Vt (16B global loads)
#pragma unroll
    for (int half = 0; half < 2; ++half) {
      const float4 p0 = *(const float4*)&Ps[w*16 + a][half*32 + qd*8];
      const float4 p1 = *(const float4*)&Ps[w*16 + a][half*32 + qd*8 + 4];
      bf16x8 pa;
      pa[0] = (short)f2b(p0.x); pa[1] = (short)f2b(p0.y);
      pa[2] = (short)f2b(p0.z); pa[3] = (short)f2b(p0.w);
      pa[4] = (short)f2b(p1.x); pa[5] = (short)f2b(p1.y);
      pa[6] = (short)f2b(p1.z); pa[7] = (short)f2b(p1.w);
      const size_t voff = (size_t)k0 + half*32 + qd*8;
      const bf16x8 v0 = *(const bf16x8*)&Vh[(size_t)(a)      * NS + voff];
      const bf16x8 v1 = *(const bf16x8*)&Vh[(size_t)(16 + a) * NS + voff];
      oc0 = __builtin_amdgcn_mfma_f32_16x16x32_bf16(pa, v0, oc0, 0, 0, 0);
      oc1 = __builtin_amdgcn_mfma_f32_16x16x32_bf16(pa, v1, oc1, 0, 0, 0);
    }
  }

  // O epilogue: D col = a (d within 16-tile), row = qd*4 + r
  const int bb = bh >> 3, hh = bh & 7;
#pragma unroll
  for (int r = 0; r < 4; ++r) {
    const size_t om = (size_t)(bb * NS + q0 + w*16 + qd*4 + r) * ND + hh*32;
    Omid[om + a]      = oc0[r];
    Omid[om + 16 + a] = oc1[r];
  }
}

// ---------------------------------------------------------------------------
// Kernel C: output projection  Omid[16384,256] @ w_out^T + b_out -> out
// ---------------------------------------------------------------------------
__global__ __launch_bounds__(256) void proj_kernel(
    const float* __restrict__ a_in, const float* __restrict__ w,
    const float* __restrict__ bias, float* __restrict__ out) {
  __shared__ float As[16][68];
  __shared__ float Bs[16][68];
  const int row0 = blockIdx.x * 64;
  const int col0 = blockIdx.y * 64;
  const int tid  = threadIdx.x;
  const int tx = tid & 15, ty = tid >> 4;
  const int lm = tid >> 2, lk = tid & 3;
  float acc[4][4] = {};
  for (int kt = 0; kt < ND; kt += 16) {
    const float4 av = *(const float4*)&a_in[(size_t)(row0 + lm) * ND + kt + lk * 4];
    const float4 bv = *(const float4*)&w[(size_t)(col0 + lm) * ND + kt + lk * 4];
    __syncthreads();
    As[lk*4+0][lm] = av.x; As[lk*4+1][lm] = av.y; As[lk*4+2][lm] = av.z; As[lk*4+3][lm] = av.w;
    Bs[lk*4+0][lm] = bv.x; Bs[lk*4+1][lm] = bv.y; Bs[lk*4+2][lm] = bv.z; Bs[lk*4+3][lm] = bv.w;
    __syncthreads();
#pragma unroll
    for (int k = 0; k < 16; ++k) {
      const float4 a4 = *(const float4*)&As[k][ty*4];
      const float4 b4 = *(const float4*)&Bs[k][tx*4];
      const float a[4] = {a4.x, a4.y, a4.z, a4.w};
      const float b[4] = {b4.x, b4.y, b4.z, b4.w};
#pragma unroll
      for (int i = 0; i < 4; ++i)
#pragma unroll
        for (int j = 0; j < 4; ++j)
          acc[i][j] = fmaf(a[i], b[j], acc[i][j]);
    }
  }
  const int n0 = col0 + tx * 4;
  const float bz[4] = {bias[n0], bias[n0+1], bias[n0+2], bias[n0+3]};
#pragma unroll
  for (int i = 0; i < 4; ++i) {
    float4 o;
    o.x = acc[i][0] + bz[0];
    o.y = acc[i][1] + bz[1];
    o.z = acc[i][2] + bz[2];
    o.w = acc[i][3] + bz[3];
    *(float4*)&out[(size_t)(row0 + ty*4 + i) * ND + n0] = o;
  }
}

// ---------------------------------------------------------------------------
extern "C" void kernel_launch(void* const* d_in, const int* in_sizes, int n_in,
                              void* d_out, int out_size, void* d_ws, size_t ws_size,
                              hipStream_t stream) {
  const float* x     = (const float*)d_in[0];
  const float* w_qkv = (const float*)d_in[1];
  const float* b_qkv = (const float*)d_in[2];
  const float* w_out = (const float*)d_in[3];
  const float* b_out = (const float*)d_in[4];
  float* out  = (float*)d_out;
  float* attn = out + OUT_ATTN;

  float* ws = (float*)d_ws;
  const size_t SZH = (size_t)NB * NH * NS * HD;  // 4,194,304 elems per tensor
  float*  Omid = ws;                             // fp32 [16384][256]
  ushort* Qb = (ushort*)(ws + OUT_ATTN);         // bf16 [bh][s][32]
  ushort* Kb = Qb + SZH;                         // bf16 [bh][s][32]
  ushort* Vt = Kb + SZH;                         // bf16 [bh][d][s]

  qkv_kernel<<<dim3(NM / 64, 768 / 64), 256, 0, stream>>>(x, w_qkv, b_qkv, Qb, Kb, Vt);
  attn_kernel<<<dim3(NB * NH, NS / 64), 256, 0, stream>>>(Qb, Kb, Vt, attn, Omid);
  proj_kernel<<<dim3(NM / 64, ND / 64), 256, 0, stream>>>(Omid, w_out, b_out, out);
}